// Round 1
// baseline (1060.511 us; speedup 1.0000x reference)
//
#include <hip/hip_runtime.h>
#include <math.h>

#define N_PIX (512 * 512)      // 262144 pixels
#define NQ (N_PIX / 4)         // 65536 pixel-quads (float4 granularity)
#define NUM_CLASSES 150
#define CF 256                 // feature channels
#define ACC_STRIDE 151         // odd stride: bank=(151*c+lab)%32 -> 2 lanes/bank, conflict-free
#define PIX_PER_BLOCK 2048
#define CHUNKS (N_PIX / PIX_PER_BLOCK)  // 128 pixel chunks
#define THREADS 1024
#define TG_PIX (PIX_PER_BLOCK / (THREADS / CF))  // 512 pixels per thread-group
#define EPS 1e-8f

// ---------------------------------------------------------------------------
// ws layout (floats):
//   [0, 76800)       sums: [2 tensors][150 classes][256 channels]
//   [76800, 77100)   counts: [2 tensors][150 classes]
//
// Key idea vs previous version: thread <-> CHANNEL ownership. For each pixel,
// the label is wave-uniform (all 64 lanes process the same pixel, different
// channels), so the LDS accumulate addresses acc[c*151 + lab] are distinct
// across lanes BY CONSTRUCTION: no same-address atomic collisions (the ~200
// cyc/waveop serializer in the previous kernel), no bank conflicts (odd
// stride). Feature loads become per-thread sequential column streams; 4
// float4 loads per iteration consume exactly one 64B line per thread.
// ---------------------------------------------------------------------------

__global__ __launch_bounds__(THREADS, 4) void scatter_kernel(
    const float* __restrict__ f_src, const float* __restrict__ f_trg,
    const int* __restrict__ l_src, const int* __restrict__ l_trg,
    float* __restrict__ sums, float* __restrict__ cnt) {
  const int tensor = blockIdx.z;
  const float* __restrict__ f = tensor ? f_trg : f_src;
  const int* __restrict__ lab = tensor ? l_trg : l_src;

  __shared__ float acc[CF * ACC_STRIDE];  // 154,624 B -> 1 block/CU
  __shared__ int chist[NUM_CLASSES];

  const int t = threadIdx.x;
  for (int i = t; i < CF * ACC_STRIDE; i += THREADS) acc[i] = 0.f;
  if (t < NUM_CLASSES) chist[t] = 0;
  __syncthreads();

  const int pix0 = blockIdx.x * PIX_PER_BLOCK;

  // Block-wide label histogram (coalesced; overlaps with the main loop --
  // no sync needed, chist is only read after the barrier below).
  for (int i = t; i < PIX_PER_BLOCK; i += THREADS)
    atomicAdd(&chist[lab[pix0 + i]], 1);

  const int c = t & (CF - 1);  // channel owned by this thread
  const int tg = t >> 8;       // 0..3: quarter of the pixel chunk
  const int qbase = (pix0 >> 2) + tg * (TG_PIX / 4);
  const float4* __restrict__ fb4 = (const float4*)f + (size_t)c * NQ;
  const int4* __restrict__ lab4 = (const int4*)lab;
  float* __restrict__ arow = &acc[c * ACC_STRIDE];

  // 512 pixels = 128 quads per thread; 4 quads (one 64B line) per iteration.
  // Loads are independent of the atomics -> compiler batches all 8 up front,
  // 8 loads in flight per wave x 16 waves covers HBM latency.
  for (int j = 0; j < TG_PIX / 4; j += 4) {
    const int q = qbase + j;
    const float4 v0 = fb4[q + 0];
    const float4 v1 = fb4[q + 1];
    const float4 v2 = fb4[q + 2];
    const float4 v3 = fb4[q + 3];
    const int4 l0 = lab4[q + 0];
    const int4 l1 = lab4[q + 1];
    const int4 l2 = lab4[q + 2];
    const int4 l3 = lab4[q + 3];
    atomicAdd(&arow[l0.x], v0.x);
    atomicAdd(&arow[l0.y], v0.y);
    atomicAdd(&arow[l0.z], v0.z);
    atomicAdd(&arow[l0.w], v0.w);
    atomicAdd(&arow[l1.x], v1.x);
    atomicAdd(&arow[l1.y], v1.y);
    atomicAdd(&arow[l1.z], v1.z);
    atomicAdd(&arow[l1.w], v1.w);
    atomicAdd(&arow[l2.x], v2.x);
    atomicAdd(&arow[l2.y], v2.y);
    atomicAdd(&arow[l2.z], v2.z);
    atomicAdd(&arow[l2.w], v2.w);
    atomicAdd(&arow[l3.x], v3.x);
    atomicAdd(&arow[l3.y], v3.y);
    atomicAdd(&arow[l3.z], v3.z);
    atomicAdd(&arow[l3.w], v3.w);
  }

  __syncthreads();

  // Flush: out[cls*256 + ch] <- acc[ch*151 + cls]. Global side coalesced;
  // LDS side stride 151*4B -> odd dword stride -> 2 lanes/bank, free.
  float* __restrict__ out = sums + tensor * (NUM_CLASSES * CF);
  for (int i = t; i < NUM_CLASSES * CF; i += THREADS) {
    const int cls = i >> 8;
    const int ch = i & (CF - 1);
    unsafeAtomicAdd(&out[i], acc[ch * ACC_STRIDE + cls]);
  }
  if (t < NUM_CLASSES) {
    const int h = chist[t];
    if (h) unsafeAtomicAdd(&cnt[tensor * NUM_CLASSES + t], (float)h);
  }
}

#define FTHREADS 1024
__global__ __launch_bounds__(FTHREADS) void finalize_kernel(
    const float* __restrict__ sums, const float* __restrict__ cnt,
    float* __restrict__ out) {
  const float* ss = sums;
  const float* st = sums + NUM_CLASSES * CF;
  const float* cs = cnt;
  const float* ct = cnt + NUM_CLASSES;
  float acc = 0.f;
  for (int i = threadIdx.x; i < NUM_CLASSES * CF; i += FTHREADS) {
    const int cls = i >> 8;  // CF == 256
    const float d = ss[i] / (cs[cls] + EPS) - st[i] / (ct[cls] + EPS);
    acc += d * d;
  }
#pragma unroll
  for (int off = 32; off > 0; off >>= 1) acc += __shfl_down(acc, off, 64);
  __shared__ float red[FTHREADS / 64];
  const int lane = threadIdx.x & 63;
  const int wid = threadIdx.x >> 6;
  if (lane == 0) red[wid] = acc;
  __syncthreads();
  if (threadIdx.x == 0) {
    float tsum = 0.f;
#pragma unroll
    for (int w = 0; w < FTHREADS / 64; ++w) tsum += red[w];
    out[0] = sqrtf(tsum);
  }
}

extern "C" void kernel_launch(void* const* d_in, const int* in_sizes, int n_in,
                              void* d_out, int out_size, void* d_ws,
                              size_t ws_size, hipStream_t stream) {
  const float* f_src = (const float*)d_in[0];
  const float* f_trg = (const float*)d_in[1];
  const int* l_src = (const int*)d_in[2];
  const int* l_trg = (const int*)d_in[3];
  float* out = (float*)d_out;

  float* sums = (float*)d_ws;                // 2 * 150 * 256 floats
  float* cnt = sums + 2 * NUM_CLASSES * CF;  // 2 * 150 floats

  const size_t zero_bytes =
      (size_t)(2 * NUM_CLASSES * CF + 2 * NUM_CLASSES) * sizeof(float);
  hipMemsetAsync(d_ws, 0, zero_bytes, stream);

  hipLaunchKernelGGL(scatter_kernel, dim3(CHUNKS, 1, 2), dim3(THREADS), 0,
                     stream, f_src, f_trg, l_src, l_trg, sums, cnt);
  hipLaunchKernelGGL(finalize_kernel, dim3(1), dim3(FTHREADS), 0, stream, sums,
                     cnt, out);
}

// Round 2
// 615.353 us; speedup vs baseline: 1.7234x; 1.7234x over previous
//
#include <hip/hip_runtime.h>
#include <math.h>

#define N_PIX (512 * 512)      // 262144 pixels
#define NQ (N_PIX / 4)         // 65536 pixel-quads (float4 granularity)
#define NUM_CLASSES 150
#define CF 256                 // feature channels
#define ACC_STRIDE 151         // row stride; index 150 = DUMP column for merged dups
#define DUMP 150
#define PIX_PER_BLOCK 2048
#define QUADS_PER_BLOCK (PIX_PER_BLOCK / 4)  // 512 quads per chunk
#define CHUNKS (N_PIX / PIX_PER_BLOCK)       // 128 pixel chunks
#define THREADS 256
#define EPS 1e-8f

// ---------------------------------------------------------------------------
// ws layout (floats):
//   [0, 76800)       sums: [2 tensors][150 classes][256 channels]
//   [76800, 77100)   counts: [2 tensors][150 classes]
//
// Round-1 post-mortem: ~205 cycles per LDS-atomic WAVE-OP in BOTH prior
// kernels (coalesced/conflicting and scattered/conflict-free alike) =>
// LDS atomics are per-lane serialized (~3 cy/lane) regardless of address
// pattern. So this version has ZERO LDS atomics: thread t exclusively owns
// channel row acc[t][0..150] and does plain read-add-write. Labels are
// wave-uniform (all lanes process the same pixel quad), so within-quad
// duplicate labels are merged in registers (branchless) and merged slots are
// redirected to the DUMP column (150) to keep the 4 RMWs race-free in-lane.
// ---------------------------------------------------------------------------

__device__ __forceinline__ void rmw_quad(float* __restrict__ arow, float4 v,
                                         int4 L) {
  float vx = v.x, vy = v.y, vz = v.z, vw = v.w;
  int ax = L.x, ay = L.y, az = L.z, aw = L.w;
  // Merge each later pixel into the earliest slot sharing its label; a merged
  // slot's RMW is redirected to the DUMP column (garbage, never read).
  if (L.y == L.x) { vx += vy; ay = DUMP; }
  if (L.z == L.x) { vx += vz; az = DUMP; }
  else if (L.z == L.y) { vy += vz; az = DUMP; }
  if (L.w == L.x) { vx += vw; aw = DUMP; }
  else if (L.w == L.y) { vy += vw; aw = DUMP; }
  else if (L.w == L.z) { vz += vw; aw = DUMP; }
  // Plain RMW: addresses distinct in-lane (distinct labels or DUMP); rows
  // distinct across lanes (exclusive channel ownership). DS ops execute in
  // program order per wave, so cross-quad same-label RAW is safe.
  const float r0 = arow[ax];
  const float r1 = arow[ay];
  const float r2 = arow[az];
  const float r3 = arow[aw];
  arow[ax] = r0 + vx;
  arow[ay] = r1 + vy;
  arow[az] = r2 + vz;
  arow[aw] = r3 + vw;
}

__global__ __launch_bounds__(THREADS, 1) void scatter_kernel(
    const float* __restrict__ f_src, const float* __restrict__ f_trg,
    const int* __restrict__ l_src, const int* __restrict__ l_trg,
    float* __restrict__ sums, float* __restrict__ cnt) {
  const int tensor = blockIdx.z;
  const float* __restrict__ f = tensor ? f_trg : f_src;
  const int* __restrict__ lab = tensor ? l_trg : l_src;

  __shared__ float acc[CF * ACC_STRIDE];  // 154,624 B -> 1 block/CU

  const int t = threadIdx.x;  // t == owned channel (exclusive acc row)
  for (int i = t; i < CF * ACC_STRIDE; i += THREADS) acc[i] = 0.f;
  __syncthreads();

  const int q0 = blockIdx.x * QUADS_PER_BLOCK;
  const float4* __restrict__ fb4 = (const float4*)f + (size_t)t * NQ;
  const int4* __restrict__ lab4 = (const int4*)lab;
  float* __restrict__ arow = &acc[t * ACC_STRIDE];

  int my_count = 0;  // occurrences of class 't' in this chunk (t<150 valid)

  // Register double-buffer: issue next iteration's 64B/thread of features
  // (+labels, wave-uniform) before running the current DS chains, so HBM
  // latency hides under the read-add-write sequences.
  int q = q0;
  float4 a0 = fb4[q + 0], a1 = fb4[q + 1], a2 = fb4[q + 2], a3 = fb4[q + 3];
  int4 b0 = lab4[q + 0], b1 = lab4[q + 1], b2 = lab4[q + 2], b3 = lab4[q + 3];

  for (int j = 0; j < QUADS_PER_BLOCK; j += 4) {
    const float4 v0 = a0, v1 = a1, v2 = a2, v3 = a3;
    const int4 L0 = b0, L1 = b1, L2 = b2, L3 = b3;
    // Prefetch next group (wraps to q0 on the last iteration; values unused).
    q = q0 + ((j + 4) & (QUADS_PER_BLOCK - 1));
    a0 = fb4[q + 0]; a1 = fb4[q + 1]; a2 = fb4[q + 2]; a3 = fb4[q + 3];
    b0 = lab4[q + 0]; b1 = lab4[q + 1]; b2 = lab4[q + 2]; b3 = lab4[q + 3];

    my_count += (L0.x == t) + (L0.y == t) + (L0.z == t) + (L0.w == t) +
                (L1.x == t) + (L1.y == t) + (L1.z == t) + (L1.w == t) +
                (L2.x == t) + (L2.y == t) + (L2.z == t) + (L2.w == t) +
                (L3.x == t) + (L3.y == t) + (L3.z == t) + (L3.w == t);

    rmw_quad(arow, v0, L0);
    rmw_quad(arow, v1, L1);
    rmw_quad(arow, v2, L2);
    rmw_quad(arow, v3, L3);
  }
  __syncthreads();

  // Flush: out[cls*256 + ch] += acc[ch*151 + cls]. Global side coalesced;
  // LDS side stride 151 dwords -> odd -> 2 lanes/bank, free.
  float* __restrict__ out = sums + tensor * (NUM_CLASSES * CF);
  for (int i = t; i < NUM_CLASSES * CF; i += THREADS) {
    const int cls = i >> 8;
    const int ch = i & (CF - 1);
    unsafeAtomicAdd(&out[i], acc[ch * ACC_STRIDE + cls]);
  }
  if (t < NUM_CLASSES)
    unsafeAtomicAdd(&cnt[tensor * NUM_CLASSES + t], (float)my_count);
}

#define FTHREADS 1024
__global__ __launch_bounds__(FTHREADS) void finalize_kernel(
    const float* __restrict__ sums, const float* __restrict__ cnt,
    float* __restrict__ out) {
  const float* ss = sums;
  const float* st = sums + NUM_CLASSES * CF;
  const float* cs = cnt;
  const float* ct = cnt + NUM_CLASSES;
  float acc = 0.f;
  for (int i = threadIdx.x; i < NUM_CLASSES * CF; i += FTHREADS) {
    const int cls = i >> 8;  // CF == 256
    const float d = ss[i] / (cs[cls] + EPS) - st[i] / (ct[cls] + EPS);
    acc += d * d;
  }
#pragma unroll
  for (int off = 32; off > 0; off >>= 1) acc += __shfl_down(acc, off, 64);
  __shared__ float red[FTHREADS / 64];
  const int lane = threadIdx.x & 63;
  const int wid = threadIdx.x >> 6;
  if (lane == 0) red[wid] = acc;
  __syncthreads();
  if (threadIdx.x == 0) {
    float tsum = 0.f;
#pragma unroll
    for (int w = 0; w < FTHREADS / 64; ++w) tsum += red[w];
    out[0] = sqrtf(tsum);
  }
}

extern "C" void kernel_launch(void* const* d_in, const int* in_sizes, int n_in,
                              void* d_out, int out_size, void* d_ws,
                              size_t ws_size, hipStream_t stream) {
  const float* f_src = (const float*)d_in[0];
  const float* f_trg = (const float*)d_in[1];
  const int* l_src = (const int*)d_in[2];
  const int* l_trg = (const int*)d_in[3];
  float* out = (float*)d_out;

  float* sums = (float*)d_ws;                // 2 * 150 * 256 floats
  float* cnt = sums + 2 * NUM_CLASSES * CF;  // 2 * 150 floats

  const size_t zero_bytes =
      (size_t)(2 * NUM_CLASSES * CF + 2 * NUM_CLASSES) * sizeof(float);
  hipMemsetAsync(d_ws, 0, zero_bytes, stream);

  hipLaunchKernelGGL(scatter_kernel, dim3(CHUNKS, 1, 2), dim3(THREADS), 0,
                     stream, f_src, f_trg, l_src, l_trg, sums, cnt);
  hipLaunchKernelGGL(finalize_kernel, dim3(1), dim3(FTHREADS), 0, stream, sums,
                     cnt, out);
}

// Round 3
// 597.007 us; speedup vs baseline: 1.7764x; 1.0307x over previous
//
#include <hip/hip_runtime.h>
#include <math.h>

#define N_PIX (512 * 512)      // 262144 pixels
#define NQ (N_PIX / 4)         // 65536 pixel-quads (float4 granularity)
#define NUM_CLASSES 150
#define CF 256                 // feature channels
#define ACC_STRIDE 151         // row stride; index 150 = DUMP column for merged dups
#define DUMP 150
#define PIX_PER_BLOCK 2048
#define QUADS_PER_BLOCK (PIX_PER_BLOCK / 4)  // 512 quads per chunk
#define CHUNKS (N_PIX / PIX_PER_BLOCK)       // 128 pixel chunks
#define THREADS 256
#define BATCH 16               // quads per buffer = 256 B per stream visit
#define EPS 1e-8f

// ---------------------------------------------------------------------------
// ws layout (floats):
//   [0, 76800)       sums: [2 tensors][150 classes][256 channels]
//   [76800, 77100)   counts: [2 tensors][150 classes]
//
// Round-2 post-mortem: atomic-free exclusive-row RMW fixed the LDS-atomic
// serializer (700 -> 226 us). Remaining gap to the 84 us stream roofline is
// the load pattern: 64 B per stream visit across 65K device-wide streams
// kills DRAM row-buffer locality and keeps only 4 KB/wave in flight. This
// version visits each stream 256 B at a time (16 x float4, double-buffered
// in two STATICALLY-indexed register arrays ~128 VGPR; free, LDS caps us at
// 1 block/CU) and stages the chunk's labels in LDS as packed bytes (one
// coalesced pre-pass; hot loop reads them via wave-uniform broadcast
// ds_read_b32). Zero LDS atomics, zero bank conflicts, same flush.
// ---------------------------------------------------------------------------

__device__ __forceinline__ void rmw_quad(float* __restrict__ arow, float4 v,
                                         int lx, int ly, int lz, int lw) {
  float vx = v.x, vy = v.y, vz = v.z, vw = v.w;
  int ax = lx, ay = ly, az = lz, aw = lw;
  // Merge each later pixel into the earliest slot sharing its label; a merged
  // slot's RMW is redirected to the DUMP column (garbage, never read).
  if (ly == lx) { vx += vy; ay = DUMP; }
  if (lz == lx) { vx += vz; az = DUMP; }
  else if (lz == ly) { vy += vz; az = DUMP; }
  if (lw == lx) { vx += vw; aw = DUMP; }
  else if (lw == ly) { vy += vw; aw = DUMP; }
  else if (lw == lz) { vz += vw; aw = DUMP; }
  // Plain RMW: addresses distinct in-lane (distinct labels or DUMP); rows
  // distinct across lanes (exclusive channel ownership). DS ops execute in
  // program order per wave, so cross-quad same-label RAW is safe.
  const float r0 = arow[ax];
  const float r1 = arow[ay];
  const float r2 = arow[az];
  const float r3 = arow[aw];
  arow[ax] = r0 + vx;
  arow[ay] = r1 + vy;
  arow[az] = r2 + vz;
  arow[aw] = r3 + vw;
}

__global__ __launch_bounds__(THREADS, 1) void scatter_kernel(
    const float* __restrict__ f_src, const float* __restrict__ f_trg,
    const int* __restrict__ l_src, const int* __restrict__ l_trg,
    float* __restrict__ sums, float* __restrict__ cnt) {
  const int tensor = blockIdx.z;
  const float* __restrict__ f = tensor ? f_trg : f_src;
  const int* __restrict__ lab = tensor ? l_trg : l_src;

  __shared__ float acc[CF * ACC_STRIDE];        // 154,624 B
  __shared__ unsigned int slab[QUADS_PER_BLOCK];  // 2 KB packed labels (u8 x4)

  const int t = threadIdx.x;  // t == owned channel (exclusive acc row)
  const int q0 = blockIdx.x * QUADS_PER_BLOCK;
  const int4* __restrict__ lab4 = (const int4*)lab;

  for (int i = t; i < CF * ACC_STRIDE; i += THREADS) acc[i] = 0.f;
  // Stage labels: coalesced int4 load, pack 4 labels (<150) into one u32.
  for (int i = t; i < QUADS_PER_BLOCK; i += THREADS) {
    const int4 L = lab4[q0 + i];
    slab[i] = (unsigned)L.x | ((unsigned)L.y << 8) | ((unsigned)L.z << 16) |
              ((unsigned)L.w << 24);
  }
  __syncthreads();

  const float4* __restrict__ fb4 = (const float4*)f + (size_t)t * NQ;
  float* __restrict__ arow = &acc[t * ACC_STRIDE];
  int my_count = 0;  // occurrences of class 't' in this chunk (t<150 valid)

#define PROCESS(BUF, JBASE)                                                  \
  _Pragma("unroll") for (int k = 0; k < BATCH; ++k) {                        \
    const unsigned pl = slab[(JBASE) + k]; /* wave-uniform broadcast */      \
    const int lx = pl & 255;                                                 \
    const int ly = (pl >> 8) & 255;                                          \
    const int lz = (pl >> 16) & 255;                                         \
    const int lw = pl >> 24;                                                 \
    my_count += (lx == t) + (ly == t) + (lz == t) + (lw == t);               \
    rmw_quad(arow, BUF[k], lx, ly, lz, lw);                                  \
  }

  // Double-buffered 256 B stream visits: two named register arrays, all
  // indices compile-time (rule: runtime-indexed arrays go to scratch).
  float4 bufA[BATCH], bufB[BATCH];
#pragma unroll
  for (int i = 0; i < BATCH; ++i) bufA[i] = fb4[q0 + i];

  for (int j = 0; j < QUADS_PER_BLOCK; j += 2 * BATCH) {
#pragma unroll
    for (int i = 0; i < BATCH; ++i)
      bufB[i] = fb4[q0 + j + BATCH + i];
    PROCESS(bufA, j)
#pragma unroll
    for (int i = 0; i < BATCH; ++i)
      bufA[i] = fb4[q0 + ((j + 2 * BATCH + i) & (QUADS_PER_BLOCK - 1))];
    PROCESS(bufB, j + BATCH)
  }
#undef PROCESS
  __syncthreads();

  // Flush: out[cls*256 + ch] += acc[ch*151 + cls]. Global side coalesced;
  // LDS side stride 151 dwords -> odd -> 2 lanes/bank, free.
  float* __restrict__ out = sums + tensor * (NUM_CLASSES * CF);
  for (int i = t; i < NUM_CLASSES * CF; i += THREADS) {
    const int cls = i >> 8;
    const int ch = i & (CF - 1);
    unsafeAtomicAdd(&out[i], acc[ch * ACC_STRIDE + cls]);
  }
  if (t < NUM_CLASSES)
    unsafeAtomicAdd(&cnt[tensor * NUM_CLASSES + t], (float)my_count);
}

#define FTHREADS 1024
__global__ __launch_bounds__(FTHREADS) void finalize_kernel(
    const float* __restrict__ sums, const float* __restrict__ cnt,
    float* __restrict__ out) {
  const float* ss = sums;
  const float* st = sums + NUM_CLASSES * CF;
  const float* cs = cnt;
  const float* ct = cnt + NUM_CLASSES;
  float acc = 0.f;
  for (int i = threadIdx.x; i < NUM_CLASSES * CF; i += FTHREADS) {
    const int cls = i >> 8;  // CF == 256
    const float d = ss[i] / (cs[cls] + EPS) - st[i] / (ct[cls] + EPS);
    acc += d * d;
  }
#pragma unroll
  for (int off = 32; off > 0; off >>= 1) acc += __shfl_down(acc, off, 64);
  __shared__ float red[FTHREADS / 64];
  const int lane = threadIdx.x & 63;
  const int wid = threadIdx.x >> 6;
  if (lane == 0) red[wid] = acc;
  __syncthreads();
  if (threadIdx.x == 0) {
    float tsum = 0.f;
#pragma unroll
    for (int w = 0; w < FTHREADS / 64; ++w) tsum += red[w];
    out[0] = sqrtf(tsum);
  }
}

extern "C" void kernel_launch(void* const* d_in, const int* in_sizes, int n_in,
                              void* d_out, int out_size, void* d_ws,
                              size_t ws_size, hipStream_t stream) {
  const float* f_src = (const float*)d_in[0];
  const float* f_trg = (const float*)d_in[1];
  const int* l_src = (const int*)d_in[2];
  const int* l_trg = (const int*)d_in[3];
  float* out = (float*)d_out;

  float* sums = (float*)d_ws;                // 2 * 150 * 256 floats
  float* cnt = sums + 2 * NUM_CLASSES * CF;  // 2 * 150 floats

  const size_t zero_bytes =
      (size_t)(2 * NUM_CLASSES * CF + 2 * NUM_CLASSES) * sizeof(float);
  hipMemsetAsync(d_ws, 0, zero_bytes, stream);

  hipLaunchKernelGGL(scatter_kernel, dim3(CHUNKS, 1, 2), dim3(THREADS), 0,
                     stream, f_src, f_trg, l_src, l_trg, sums, cnt);
  hipLaunchKernelGGL(finalize_kernel, dim3(1), dim3(FTHREADS), 0, stream, sums,
                     cnt, out);
}